// Round 4
// baseline (303.086 us; speedup 1.0000x reference)
//
#include <hip/hip_runtime.h>
#include <hip/hip_bf16.h>

typedef __attribute__((ext_vector_type(8))) short short8;
typedef __attribute__((ext_vector_type(4))) short short4x;
typedef __attribute__((ext_vector_type(4))) float floatx4;

__device__ __forceinline__ short f2bf(float f) {
    unsigned u = __float_as_uint(f);
    u = u + 0x7fffu + ((u >> 16) & 1u);
    return (short)(u >> 16);
}
// truncating convert (values >=0, used for P only)
__device__ __forceinline__ short f2bf_rz(float f) {
    return (short)(__float_as_uint(f) >> 16);
}

static constexpr int B_ = 4, S_ = 2048, D_ = 1024, H_ = 16, DH_ = 64;
// Q pre-scale: 1/sqrt(DH) * log2(e), so attention scores are in log2 domain
static constexpr float QSCALE = 0.125f * 1.4426950408889634f;

// ---------------------------------------------------------------------------
// x convert: f32 -> bf16, 8 elements/thread
// ---------------------------------------------------------------------------
__global__ __launch_bounds__(256) void convert_x(const float* __restrict__ in,
                                                 short* __restrict__ out, int n8) {
    int i = blockIdx.x * 256 + threadIdx.x;
    if (i >= n8) return;
    const float4* p = (const float4*)(in + (size_t)i * 8);
    float4 a = p[0], b = p[1];
    short8 v;
    v[0] = f2bf(a.x); v[1] = f2bf(a.y); v[2] = f2bf(a.z); v[3] = f2bf(a.w);
    v[4] = f2bf(b.x); v[5] = f2bf(b.y); v[6] = f2bf(b.z); v[7] = f2bf(b.w);
    *(short8*)(out + (size_t)i * 8) = v;
}

// ---------------------------------------------------------------------------
// Merged weight prep: transpose + f32->bf16 for Wq/Wk/Wv (z=0..2, y=head) and
// Wo (z=3, y=n-tile). grid (16, 16, 4).
// ---------------------------------------------------------------------------
__global__ __launch_bounds__(256) void prep_weights(const float* __restrict__ Wq,
                                                    const float* __restrict__ Wk,
                                                    const float* __restrict__ Wv,
                                                    const float* __restrict__ Wo,
                                                    short* __restrict__ WqT,
                                                    short* __restrict__ WkT,
                                                    short* __restrict__ WvT,
                                                    short* __restrict__ WoT) {
    __shared__ alignas(16) float t[64 * 68];
    int z = blockIdx.z;
    const float* in;
    short* out;
    int N, M = D_, n0;
    if (z < 3) {
        const float* I = (z == 0) ? Wq : (z == 1) ? Wk : Wv;
        short* O = (z == 0) ? WqT : (z == 1) ? WkT : WvT;
        in = I + (size_t)blockIdx.y * D_ * DH_;
        out = O + (size_t)blockIdx.y * D_ * DH_;
        N = DH_; n0 = 0;
    } else {
        in = Wo; out = WoT; N = D_; n0 = blockIdx.y * 64;
    }
    int m0 = blockIdx.x * 64;
    int tid = threadIdx.x;
#pragma unroll
    for (int i = 0; i < 4; ++i) {
        int c = tid + i * 256;
        int row = c >> 4, c4 = (c & 15) * 4;
        float4 v = *(const float4*)(in + (size_t)(m0 + row) * N + n0 + c4);
        *(float4*)(t + row * 68 + c4) = v;
    }
    __syncthreads();
#pragma unroll
    for (int i = 0; i < 2; ++i) {
        int c = tid + i * 256;
        int row = c >> 3, c8 = (c & 7) * 8;
        short8 v;
#pragma unroll
        for (int j = 0; j < 8; ++j) v[j] = f2bf(t[(c8 + j) * 68 + row]);
        *(short8*)(out + (size_t)(n0 + row) * M + m0 + c8) = v;
    }
}

// ---------------------------------------------------------------------------
// m97-style 128x128 GEMM core with XOR-swizzled LDS chunks (validated r6:
// conflicts 1.9e7 -> 2e5).
// ---------------------------------------------------------------------------
__device__ __forceinline__ void gemm128_core(const short* __restrict__ A,
                                             const short* __restrict__ Bm,
                                             short* ldsA, short* ldsB,
                                             int m0, int n0,
                                             floatx4 (&acc)[4][4],
                                             int w, int lane, int quad, int lm) {
    const int K = 1024;
    int wm = (w >> 1) * 64, wn = (w & 1) * 64;
    int rsub = lane >> 3;                       // row-within-8-group
    int csw = ((lane & 7) ^ rsub) * 8;          // swizzled global k-chunk offset (shorts)
    int lmx = lm & 7;                           // reader swizzle key
    for (int k0 = 0; k0 < K; k0 += 64) {
#pragma unroll
        for (int i = 0; i < 4; ++i) {
            int r0 = w * 32 + i * 8;
            const short* ga = A + (size_t)(m0 + r0 + rsub) * K + k0 + csw;
            __builtin_amdgcn_global_load_lds((const __attribute__((address_space(1))) void*)ga,
                                             (__attribute__((address_space(3))) void*)(ldsA + r0 * 64),
                                             16, 0, 0);
            const short* gb = Bm + (size_t)(n0 + r0 + rsub) * K + k0 + csw;
            __builtin_amdgcn_global_load_lds((const __attribute__((address_space(1))) void*)gb,
                                             (__attribute__((address_space(3))) void*)(ldsB + r0 * 64),
                                             16, 0, 0);
        }
        __syncthreads();
#pragma unroll
        for (int ks = 0; ks < 2; ++ks) {
            short8 am[4], bn[4];
#pragma unroll
            for (int i = 0; i < 4; ++i)
                am[i] = *(const short8*)(ldsA + (wm + i * 16 + lm) * 64 + (((ks * 4 + quad) ^ lmx) << 3));
#pragma unroll
            for (int i = 0; i < 4; ++i)
                bn[i] = *(const short8*)(ldsB + (wn + i * 16 + lm) * 64 + (((ks * 4 + quad) ^ lmx) << 3));
#pragma unroll
            for (int mi = 0; mi < 4; ++mi)
#pragma unroll
                for (int ni = 0; ni < 4; ++ni)
                    acc[mi][ni] = __builtin_amdgcn_mfma_f32_16x16x32_bf16(am[mi], bn[ni], acc[mi][ni], 0, 0, 0);
        }
        __syncthreads();
    }
}

// ---------------------------------------------------------------------------
// QKV projection: grid (64, 8, 3). A = xb [8192][1024]. B = W?T [1024 n][1024 k].
// z=0 -> Q[b,h,s,e] pre-scaled by QSCALE; z=1 -> K[b,h,s,e]; z=2 -> VT[(b*1024+n)][s]
// ---------------------------------------------------------------------------
__global__ __launch_bounds__(256, 4) void qkv_gemm128(const short* __restrict__ xb,
                                                      const short* __restrict__ WqT,
                                                      const short* __restrict__ WkT,
                                                      const short* __restrict__ WvT,
                                                      short* __restrict__ Q,
                                                      short* __restrict__ K,
                                                      short* __restrict__ VT) {
    __shared__ alignas(16) short lds[16384];  // 32 KB: staging A|B, reused as epilogue bounce
    short* ldsA = lds;
    short* ldsB = lds + 8192;
    int m0 = blockIdx.x * 128, n0 = blockIdx.y * 128, z = blockIdx.z;
    const short* Bm = (z == 0) ? WqT : (z == 1) ? WkT : WvT;
    int tid = threadIdx.x, w = tid >> 6, lane = tid & 63, quad = lane >> 4, lm = lane & 15;

    floatx4 acc[4][4];
#pragma unroll
    for (int mi = 0; mi < 4; ++mi)
#pragma unroll
        for (int ni = 0; ni < 4; ++ni) acc[mi][ni] = (floatx4)0.0f;

    gemm128_core(xb, Bm, ldsA, ldsB, m0, n0, acc, w, lane, quad, lm);

    int wm = (w >> 1) * 64, wn = (w & 1) * 64;
    int b = m0 >> 11;
    int sbase = m0 & 2047;

    if (z < 2) {
        short* O = (z == 0) ? Q : K;
        float scale = (z == 0) ? QSCALE : 1.0f;
        short* t = lds;  // 128 x 68
#pragma unroll
        for (int ph = 0; ph < 2; ++ph) {
            if (ph) __syncthreads();
            if ((w & 1) == ph) {
#pragma unroll
                for (int mi = 0; mi < 4; ++mi)
#pragma unroll
                    for (int ni = 0; ni < 4; ++ni)
#pragma unroll
                        for (int r = 0; r < 4; ++r)
                            t[(wm + mi * 16 + quad * 4 + r) * 68 + ni * 16 + lm] =
                                f2bf(acc[mi][ni][r] * scale);
            }
            __syncthreads();
            int h = (n0 + ph * 64) >> 6;
            size_t obase = ((size_t)(b * 16 + h) * 2048 + sbase) * 64;
#pragma unroll
            for (int i = 0; i < 4; ++i) {
                int c = tid + i * 256;
                int m = c >> 3, e8 = (c & 7) * 8;
                short8 v = *(const short8*)(t + m * 68 + e8);
                *(short8*)(O + obase + (size_t)m * 64 + e8) = v;
            }
        }
    } else {
        // transpose 128x128 tile through LDS (two 64-n halves) -> VT[b*1024+n][s]
        short* t = lds;  // 64 x 136
#pragma unroll
        for (int ph = 0; ph < 2; ++ph) {
            if (ph) __syncthreads();
            if ((w & 1) == ph) {
#pragma unroll
                for (int mi = 0; mi < 4; ++mi)
#pragma unroll
                    for (int ni = 0; ni < 4; ++ni) {
                        int nl = ni * 16 + lm;
#pragma unroll
                        for (int r = 0; r < 4; ++r) {
                            int ml = wm + mi * 16 + quad * 4 + r;
                            t[nl * 136 + ml] = f2bf(acc[mi][ni][r]);
                        }
                    }
            }
            __syncthreads();
#pragma unroll
            for (int i = 0; i < 4; ++i) {
                int c = tid + i * 256;
                int rowl = c >> 4, colc = (c & 15) * 8;
                short8 v = *(const short8*)(t + rowl * 136 + colc);
                size_t n = n0 + ph * 64 + rowl;
                *(short8*)(VT + ((size_t)b * 1024 + n) * 2048 + sbase + colc) = v;
            }
        }
    }
}

// ---------------------------------------------------------------------------
// Output projection: out[8192][1024] f32 = CC @ WoT^T + bo. grid (64, 8).
// ---------------------------------------------------------------------------
__global__ __launch_bounds__(256, 4) void outproj128(const short* __restrict__ CC,
                                                     const short* __restrict__ WoT,
                                                     const float* __restrict__ bo,
                                                     float* __restrict__ out) {
    __shared__ alignas(16) short lds[16384];
    short* ldsA = lds;
    short* ldsB = lds + 8192;
    int m0 = blockIdx.x * 128, n0 = blockIdx.y * 128;
    int tid = threadIdx.x, w = tid >> 6, lane = tid & 63, quad = lane >> 4, lm = lane & 15;

    floatx4 acc[4][4];
#pragma unroll
    for (int mi = 0; mi < 4; ++mi)
#pragma unroll
        for (int ni = 0; ni < 4; ++ni) acc[mi][ni] = (floatx4)0.0f;

    gemm128_core(CC, WoT, ldsA, ldsB, m0, n0, acc, w, lane, quad, lm);

    int wm = (w >> 1) * 64, wn = (w & 1) * 64;
#pragma unroll
    for (int mi = 0; mi < 4; ++mi)
#pragma unroll
        for (int ni = 0; ni < 4; ++ni) {
            int n = n0 + wn + ni * 16 + lm;
            float bb = bo[n];
#pragma unroll
            for (int r = 0; r < 4; ++r) {
                int m = m0 + wm + mi * 16 + quad * 4 + r;
                out[(size_t)m * 1024 + n] = acc[mi][ni][r] + bb;
            }
        }
}

// ---------------------------------------------------------------------------
// Causal flash attention v7: ONE 128-row q-tile per block, 4 waves x 32 q-rows.
// r3 lesson: the old grid (8, B*H)=512 blocks could never exceed 2 blocks/CU
// on 256 CUs regardless of LDS capacity — the 48 KB diet bought nothing.
// Now grid (64 bh, 16 qt) = 1024 blocks -> 3 blocks/CU (LDS-limited) actually
// reachable. qt = 15 - blockIdx.y so heavy tiles dispatch first (light tail).
// bh = blockIdx.x fastest-varying: blocks sharing bh are 64 apart -> same XCD
// (64 % 8 == 0) -> each XCD's 8 bh x 512 KB K+V = 4 MB = its L2.
// Register diet retained (r1/r2: kf[8][2] in regs -> spill at the 168-reg cap):
// K-frags read from LDS right before their MFMAs; sc in groups of 4;
// Pt is a 16 KB wave-private buffer reused across the two q-halves.
// LDS: Kt 16K + Vt 16K + Pt 16K = 48 KB -> 3 blocks/CU.
// ---------------------------------------------------------------------------
__global__ __launch_bounds__(256, 3) void attn_kernel(const short* __restrict__ Q,
                                                      const short* __restrict__ Kb,
                                                      const short* __restrict__ VT,
                                                      short* __restrict__ CC) {
    __shared__ alignas(16) short Kt[128 * 64];   // swizzled chunks
    __shared__ alignas(16) short Vt[64 * 128];   // swizzled chunks
    __shared__ alignas(16) short Pt[64 * 128];   // swizzled chunks, wave-private 16 rows, reused per q-half
    int bh = blockIdx.x;
    int qt = 15 - blockIdx.y;
    int b = bh >> 4, h = bh & 15;
    int tid = threadIdx.x;
    int w = tid >> 6, l = tid & 63;
    int quad = l >> 4, lm = l & 15;
    int lmx = lm & 7;
    int rsub = l >> 3;              // K staging row-within-8
    int csw = ((l & 7) ^ rsub) * 8; // K staging swizzled chunk offset
    int vr4 = l >> 4;               // V staging row-within-4
    int vc = l & 15;

    const short* Qbh = Q + (size_t)bh * S_ * DH_;
    const short* Kbh = Kb + (size_t)bh * S_ * DH_;
    const short* Vbh = VT + (size_t)bh * 64 * S_;

    int q0 = qt * 128;

    short8 qa[2][2];
#pragma unroll
    for (int nq = 0; nq < 2; ++nq) {
        const short* Qrow = Qbh + (size_t)(q0 + nq * 64 + w * 16 + lm) * DH_;
        qa[nq][0] = *(const short8*)(Qrow + quad * 8);
        qa[nq][1] = *(const short8*)(Qrow + 32 + quad * 8);
    }

    floatx4 acc_o[2][4];
#pragma unroll
    for (int nq = 0; nq < 2; ++nq)
#pragma unroll
        for (int ct = 0; ct < 4; ++ct) acc_o[nq][ct] = (floatx4)0.0f;
    float lsum[2] = {0.0f, 0.0f};

    int nkt = qt + 1;
    for (int kt = 0; kt < nkt; ++kt) {
        int t0 = kt * 128;
        // stage Kt[128][64] (rows contiguous) and Vt[64][128] (rows stride S_)
        const short* Ktile = Kbh + (size_t)t0 * DH_;
#pragma unroll
        for (int i = 0; i < 4; ++i) {
            int r0 = w * 32 + i * 8;
            const short* ga = Ktile + (size_t)(r0 + rsub) * 64 + csw;
            __builtin_amdgcn_global_load_lds((const __attribute__((address_space(1))) void*)ga,
                                             (__attribute__((address_space(3))) void*)(Kt + r0 * 64),
                                             16, 0, 0);
        }
#pragma unroll
        for (int i = 0; i < 4; ++i) {
            int r0v = w * 16 + i * 4;
            int row = r0v + vr4;
            const short* gv = Vbh + (size_t)row * S_ + t0 + ((vc ^ (row & 7)) * 8);
            __builtin_amdgcn_global_load_lds((const __attribute__((address_space(1))) void*)gv,
                                             (__attribute__((address_space(3))) void*)(Vt + r0v * 128),
                                             16, 0, 0);
        }
        __syncthreads();

        bool last = (kt == nkt - 1);
        int prow = w * 16 + lm;
#pragma unroll
        for (int nq = 0; nq < 2; ++nq) {
#pragma unroll
            for (int mg = 0; mg < 2; ++mg) {
                floatx4 sc[4];
                __builtin_amdgcn_s_setprio(1);
#pragma unroll
                for (int mi = 0; mi < 4; ++mi) {
                    int mt = mg * 4 + mi;
                    const short* krow = Kt + (mt * 16 + lm) * 64;
                    short8 k0 = *(const short8*)(krow + ((quad ^ lmx) << 3));
                    short8 k1 = *(const short8*)(krow + (((4 + quad) ^ lmx) << 3));
                    floatx4 t = (floatx4)0.0f;
                    t = __builtin_amdgcn_mfma_f32_16x16x32_bf16(k0, qa[nq][0], t, 0, 0, 0);
                    t = __builtin_amdgcn_mfma_f32_16x16x32_bf16(k1, qa[nq][1], t, 0, 0, 0);
                    sc[mi] = t;  // S^T: row=t (quad*4+r), col=q (lm)
                }
                __builtin_amdgcn_s_setprio(0);
                if (last) {
                    int q_ = q0 + nq * 64 + w * 16 + lm;
#pragma unroll
                    for (int mi = 0; mi < 4; ++mi)
#pragma unroll
                        for (int r = 0; r < 4; ++r) {
                            int t_ = t0 + (mg * 4 + mi) * 16 + quad * 4 + r;
                            if (t_ > q_) sc[mi][r] = -INFINITY;
                        }
                }
#pragma unroll
                for (int mi = 0; mi < 4; ++mi) {
                    float p0 = exp2f(sc[mi][0]);
                    float p1 = exp2f(sc[mi][1]);
                    float p2 = exp2f(sc[mi][2]);
                    float p3 = exp2f(sc[mi][3]);
                    lsum[nq] += (p0 + p1) + (p2 + p3);
                    short4x pk;
                    pk[0] = f2bf_rz(p0); pk[1] = f2bf_rz(p1);
                    pk[2] = f2bf_rz(p2); pk[3] = f2bf_rz(p3);
                    int c = (mg * 4 + mi) * 2 + (quad >> 1);
                    *(short4x*)(Pt + prow * 128 + ((c ^ lmx) << 3) + (quad & 1) * 4) = pk;
                }
            }
            // Pt rows are wave-private -> no barrier between write and read;
            // same-wave DS ops are in-order and the compiler cannot prove
            // no-alias (identical addresses across nq) so order is kept.
            short8 pa[4];
#pragma unroll
            for (int ks = 0; ks < 4; ++ks)
                pa[ks] = *(const short8*)(Pt + prow * 128 + (((ks * 4 + quad) ^ lmx) << 3));
            __builtin_amdgcn_s_setprio(1);
#pragma unroll
            for (int ct = 0; ct < 4; ++ct) {
                const short* vrow = Vt + (ct * 16 + lm) * 128;
#pragma unroll
                for (int ks = 0; ks < 4; ++ks) {
                    short8 v = *(const short8*)(vrow + (((ks * 4 + quad) ^ lmx) << 3));
                    acc_o[nq][ct] = __builtin_amdgcn_mfma_f32_16x16x32_bf16(pa[ks], v, acc_o[nq][ct], 0, 0, 0);
                }
            }
            __builtin_amdgcn_s_setprio(0);
        }
        __syncthreads();  // protects Kt/Vt restage next iteration
    }

    // reduce l across quads (lanes with same lm), then 1/l
    float invl[2];
#pragma unroll
    for (int nq = 0; nq < 2; ++nq) {
        float lr = lsum[nq];
        lr += __shfl_xor(lr, 16);
        lr += __shfl_xor(lr, 32);
        invl[nq] = 1.0f / lr;
    }

#pragma unroll
    for (int nq = 0; nq < 2; ++nq) {
#pragma unroll
        for (int r = 0; r < 4; ++r) {
            float iv = __shfl(invl[nq], quad * 4 + r);  // l for q-row quad*4+r
            int row = q0 + nq * 64 + w * 16 + quad * 4 + r;
            short* OC = CC + ((size_t)b * S_ + row) * D_ + h * DH_;
#pragma unroll
            for (int ct = 0; ct < 4; ++ct)
                OC[ct * 16 + lm] = f2bf(acc_o[nq][ct][r] * iv);
        }
    }
}

extern "C" void kernel_launch(void* const* d_in, const int* in_sizes, int n_in,
                              void* d_out, int out_size, void* d_ws, size_t ws_size,
                              hipStream_t stream) {
    const float* x  = (const float*)d_in[0];
    const float* Wq = (const float*)d_in[1];
    const float* Wk = (const float*)d_in[2];
    const float* Wv = (const float*)d_in[3];
    const float* Wo = (const float*)d_in[4];
    const float* bo = (const float*)d_in[5];
    float* out = (float*)d_out;
    short* ws = (short*)d_ws;

    const size_t WSZ = (size_t)H_ * D_ * DH_;        // 1,048,576
    const size_t QSZ = (size_t)B_ * H_ * S_ * DH_;   // 8,388,608
    short* WqT = ws;
    short* WkT = WqT + WSZ;
    short* WvT = WkT + WSZ;
    short* WoT = WvT + WSZ;
    short* xb  = WoT + (size_t)D_ * D_;
    short* Qb  = xb + (size_t)B_ * S_ * D_;
    short* Kb  = Qb + QSZ;
    short* VTb = Kb + QSZ;
    short* CCb = VTb + QSZ;

    convert_x<<<(B_ * S_ * D_ / 8 + 255) / 256, 256, 0, stream>>>(x, xb, B_ * S_ * D_ / 8);
    prep_weights<<<dim3(16, 16, 4), 256, 0, stream>>>(Wq, Wk, Wv, Wo, WqT, WkT, WvT, WoT);
    qkv_gemm128<<<dim3(64, 8, 3), 256, 0, stream>>>(xb, WqT, WkT, WvT, Qb, Kb, VTb);
    attn_kernel<<<dim3(64, 16), 256, 0, stream>>>(Qb, Kb, VTb, CCb);
    outproj128<<<dim3(64, 8), 256, 0, stream>>>(CCb, WoT, bo, out);
}

// Round 5
// 295.233 us; speedup vs baseline: 1.0266x; 1.0266x over previous
//
#include <hip/hip_runtime.h>
#include <hip/hip_bf16.h>

typedef __attribute__((ext_vector_type(8))) short short8;
typedef __attribute__((ext_vector_type(4))) short short4x;
typedef __attribute__((ext_vector_type(4))) float floatx4;

__device__ __forceinline__ short f2bf(float f) {
    unsigned u = __float_as_uint(f);
    u = u + 0x7fffu + ((u >> 16) & 1u);
    return (short)(u >> 16);
}
// truncating convert (values >=0, used for P only)
__device__ __forceinline__ short f2bf_rz(float f) {
    return (short)(__float_as_uint(f) >> 16);
}

static constexpr int B_ = 4, S_ = 2048, D_ = 1024, H_ = 16, DH_ = 64;
// Q pre-scale: 1/sqrt(DH) * log2(e), so attention scores are in log2 domain
static constexpr float QSCALE = 0.125f * 1.4426950408889634f;

// ---------------------------------------------------------------------------
// x convert: f32 -> bf16, 8 elements/thread
// ---------------------------------------------------------------------------
__global__ __launch_bounds__(256) void convert_x(const float* __restrict__ in,
                                                 short* __restrict__ out, int n8) {
    int i = blockIdx.x * 256 + threadIdx.x;
    if (i >= n8) return;
    const float4* p = (const float4*)(in + (size_t)i * 8);
    float4 a = p[0], b = p[1];
    short8 v;
    v[0] = f2bf(a.x); v[1] = f2bf(a.y); v[2] = f2bf(a.z); v[3] = f2bf(a.w);
    v[4] = f2bf(b.x); v[5] = f2bf(b.y); v[6] = f2bf(b.z); v[7] = f2bf(b.w);
    *(short8*)(out + (size_t)i * 8) = v;
}

// ---------------------------------------------------------------------------
// Merged weight prep: transpose + f32->bf16 for Wq/Wk/Wv (z=0..2, y=head) and
// Wo (z=3, y=n-tile). grid (16, 16, 4).
// ---------------------------------------------------------------------------
__global__ __launch_bounds__(256) void prep_weights(const float* __restrict__ Wq,
                                                    const float* __restrict__ Wk,
                                                    const float* __restrict__ Wv,
                                                    const float* __restrict__ Wo,
                                                    short* __restrict__ WqT,
                                                    short* __restrict__ WkT,
                                                    short* __restrict__ WvT,
                                                    short* __restrict__ WoT) {
    __shared__ alignas(16) float t[64 * 68];
    int z = blockIdx.z;
    const float* in;
    short* out;
    int N, M = D_, n0;
    if (z < 3) {
        const float* I = (z == 0) ? Wq : (z == 1) ? Wk : Wv;
        short* O = (z == 0) ? WqT : (z == 1) ? WkT : WvT;
        in = I + (size_t)blockIdx.y * D_ * DH_;
        out = O + (size_t)blockIdx.y * D_ * DH_;
        N = DH_; n0 = 0;
    } else {
        in = Wo; out = WoT; N = D_; n0 = blockIdx.y * 64;
    }
    int m0 = blockIdx.x * 64;
    int tid = threadIdx.x;
#pragma unroll
    for (int i = 0; i < 4; ++i) {
        int c = tid + i * 256;
        int row = c >> 4, c4 = (c & 15) * 4;
        float4 v = *(const float4*)(in + (size_t)(m0 + row) * N + n0 + c4);
        *(float4*)(t + row * 68 + c4) = v;
    }
    __syncthreads();
#pragma unroll
    for (int i = 0; i < 2; ++i) {
        int c = tid + i * 256;
        int row = c >> 3, c8 = (c & 7) * 8;
        short8 v;
#pragma unroll
        for (int j = 0; j < 8; ++j) v[j] = f2bf(t[(c8 + j) * 68 + row]);
        *(short8*)(out + (size_t)(n0 + row) * M + m0 + c8) = v;
    }
}

// ---------------------------------------------------------------------------
// m97-style 128x128 GEMM core with XOR-swizzled LDS chunks (validated r6:
// conflicts 1.9e7 -> 2e5).
// ---------------------------------------------------------------------------
__device__ __forceinline__ void gemm128_core(const short* __restrict__ A,
                                             const short* __restrict__ Bm,
                                             short* ldsA, short* ldsB,
                                             int m0, int n0,
                                             floatx4 (&acc)[4][4],
                                             int w, int lane, int quad, int lm) {
    const int K = 1024;
    int wm = (w >> 1) * 64, wn = (w & 1) * 64;
    int rsub = lane >> 3;                       // row-within-8-group
    int csw = ((lane & 7) ^ rsub) * 8;          // swizzled global k-chunk offset (shorts)
    int lmx = lm & 7;                           // reader swizzle key
    for (int k0 = 0; k0 < K; k0 += 64) {
#pragma unroll
        for (int i = 0; i < 4; ++i) {
            int r0 = w * 32 + i * 8;
            const short* ga = A + (size_t)(m0 + r0 + rsub) * K + k0 + csw;
            __builtin_amdgcn_global_load_lds((const __attribute__((address_space(1))) void*)ga,
                                             (__attribute__((address_space(3))) void*)(ldsA + r0 * 64),
                                             16, 0, 0);
            const short* gb = Bm + (size_t)(n0 + r0 + rsub) * K + k0 + csw;
            __builtin_amdgcn_global_load_lds((const __attribute__((address_space(1))) void*)gb,
                                             (__attribute__((address_space(3))) void*)(ldsB + r0 * 64),
                                             16, 0, 0);
        }
        __syncthreads();
#pragma unroll
        for (int ks = 0; ks < 2; ++ks) {
            short8 am[4], bn[4];
#pragma unroll
            for (int i = 0; i < 4; ++i)
                am[i] = *(const short8*)(ldsA + (wm + i * 16 + lm) * 64 + (((ks * 4 + quad) ^ lmx) << 3));
#pragma unroll
            for (int i = 0; i < 4; ++i)
                bn[i] = *(const short8*)(ldsB + (wn + i * 16 + lm) * 64 + (((ks * 4 + quad) ^ lmx) << 3));
#pragma unroll
            for (int mi = 0; mi < 4; ++mi)
#pragma unroll
                for (int ni = 0; ni < 4; ++ni)
                    acc[mi][ni] = __builtin_amdgcn_mfma_f32_16x16x32_bf16(am[mi], bn[ni], acc[mi][ni], 0, 0, 0);
        }
        __syncthreads();
    }
}

// ---------------------------------------------------------------------------
// QKV projection: grid (64, 8, 3). A = xb [8192][1024]. B = W?T [1024 n][1024 k].
// z=0 -> Q[b,h,s,e] pre-scaled by QSCALE; z=1 -> K[b,h,s,e]; z=2 -> VT[(b*1024+n)][s]
// ---------------------------------------------------------------------------
__global__ __launch_bounds__(256, 4) void qkv_gemm128(const short* __restrict__ xb,
                                                      const short* __restrict__ WqT,
                                                      const short* __restrict__ WkT,
                                                      const short* __restrict__ WvT,
                                                      short* __restrict__ Q,
                                                      short* __restrict__ K,
                                                      short* __restrict__ VT) {
    __shared__ alignas(16) short lds[16384];  // 32 KB: staging A|B, reused as epilogue bounce
    short* ldsA = lds;
    short* ldsB = lds + 8192;
    int m0 = blockIdx.x * 128, n0 = blockIdx.y * 128, z = blockIdx.z;
    const short* Bm = (z == 0) ? WqT : (z == 1) ? WkT : WvT;
    int tid = threadIdx.x, w = tid >> 6, lane = tid & 63, quad = lane >> 4, lm = lane & 15;

    floatx4 acc[4][4];
#pragma unroll
    for (int mi = 0; mi < 4; ++mi)
#pragma unroll
        for (int ni = 0; ni < 4; ++ni) acc[mi][ni] = (floatx4)0.0f;

    gemm128_core(xb, Bm, ldsA, ldsB, m0, n0, acc, w, lane, quad, lm);

    int wm = (w >> 1) * 64, wn = (w & 1) * 64;
    int b = m0 >> 11;
    int sbase = m0 & 2047;

    if (z < 2) {
        short* O = (z == 0) ? Q : K;
        float scale = (z == 0) ? QSCALE : 1.0f;
        short* t = lds;  // 128 x 68
#pragma unroll
        for (int ph = 0; ph < 2; ++ph) {
            if (ph) __syncthreads();
            if ((w & 1) == ph) {
#pragma unroll
                for (int mi = 0; mi < 4; ++mi)
#pragma unroll
                    for (int ni = 0; ni < 4; ++ni)
#pragma unroll
                        for (int r = 0; r < 4; ++r)
                            t[(wm + mi * 16 + quad * 4 + r) * 68 + ni * 16 + lm] =
                                f2bf(acc[mi][ni][r] * scale);
            }
            __syncthreads();
            int h = (n0 + ph * 64) >> 6;
            size_t obase = ((size_t)(b * 16 + h) * 2048 + sbase) * 64;
#pragma unroll
            for (int i = 0; i < 4; ++i) {
                int c = tid + i * 256;
                int m = c >> 3, e8 = (c & 7) * 8;
                short8 v = *(const short8*)(t + m * 68 + e8);
                *(short8*)(O + obase + (size_t)m * 64 + e8) = v;
            }
        }
    } else {
        // transpose 128x128 tile through LDS (two 64-n halves) -> VT[b*1024+n][s]
        short* t = lds;  // 64 x 136
#pragma unroll
        for (int ph = 0; ph < 2; ++ph) {
            if (ph) __syncthreads();
            if ((w & 1) == ph) {
#pragma unroll
                for (int mi = 0; mi < 4; ++mi)
#pragma unroll
                    for (int ni = 0; ni < 4; ++ni) {
                        int nl = ni * 16 + lm;
#pragma unroll
                        for (int r = 0; r < 4; ++r) {
                            int ml = wm + mi * 16 + quad * 4 + r;
                            t[nl * 136 + ml] = f2bf(acc[mi][ni][r]);
                        }
                    }
            }
            __syncthreads();
#pragma unroll
            for (int i = 0; i < 4; ++i) {
                int c = tid + i * 256;
                int rowl = c >> 4, colc = (c & 15) * 8;
                short8 v = *(const short8*)(t + rowl * 136 + colc);
                size_t n = n0 + ph * 64 + rowl;
                *(short8*)(VT + ((size_t)b * 1024 + n) * 2048 + sbase + colc) = v;
            }
        }
    }
}

// ---------------------------------------------------------------------------
// Output projection: out[8192][1024] f32 = CC @ WoT^T + bo. grid (64, 8).
// ---------------------------------------------------------------------------
__global__ __launch_bounds__(256, 4) void outproj128(const short* __restrict__ CC,
                                                     const short* __restrict__ WoT,
                                                     const float* __restrict__ bo,
                                                     float* __restrict__ out) {
    __shared__ alignas(16) short lds[16384];
    short* ldsA = lds;
    short* ldsB = lds + 8192;
    int m0 = blockIdx.x * 128, n0 = blockIdx.y * 128;
    int tid = threadIdx.x, w = tid >> 6, lane = tid & 63, quad = lane >> 4, lm = lane & 15;

    floatx4 acc[4][4];
#pragma unroll
    for (int mi = 0; mi < 4; ++mi)
#pragma unroll
        for (int ni = 0; ni < 4; ++ni) acc[mi][ni] = (floatx4)0.0f;

    gemm128_core(CC, WoT, ldsA, ldsB, m0, n0, acc, w, lane, quad, lm);

    int wm = (w >> 1) * 64, wn = (w & 1) * 64;
#pragma unroll
    for (int mi = 0; mi < 4; ++mi)
#pragma unroll
        for (int ni = 0; ni < 4; ++ni) {
            int n = n0 + wn + ni * 16 + lm;
            float bb = bo[n];
#pragma unroll
            for (int r = 0; r < 4; ++r) {
                int m = m0 + wm + mi * 16 + quad * 4 + r;
                out[(size_t)m * 1024 + n] = acc[mi][ni][r] + bb;
            }
        }
}

// ---------------------------------------------------------------------------
// Causal flash attention v8: ONE 128-row q-tile per block, 4 waves x 32 q-rows.
// Grid (64 bh, 16 qt) = 1024 blocks: 3 blocks/CU reachable; qt = 15-y so heavy
// tiles dispatch first; bh fastest-varying pins each bh's K/V to one XCD L2
// (v7 measured: FETCH 146 -> 52 MB).
// v7 lesson: at 3 blocks/CU the LDS pipe saturates if K is re-read per q-half
// (~80 LDS ops/k-tile/wave). v8 restores r0's LDS economy (56 ops) WITHOUT the
// r1/r2 register blowup by splitting each k-tile into two mt-halves (mg):
//   per mg: kf[4][2] (32 VGPR, transient) from LDS, reused for BOTH q-halves;
//           QK -> mask -> exp2 -> P-write into Pt[128][64] (rows = nq*64+wave
//           rows -> race-free, 16 KB); pa[2][2]; partial PV with each V
//           fragment read ONCE and shared across both q-halves.
// K read 1x, V read 1x, P 1x write + 1x read per k-tile == r0's traffic.
// Peak regs ~145-160 < 168 cap of (256,3) -> no spill (r2's kf[8][2] was 180+).
// LDS: Kt 16K + Vt 16K + Pt 16K = 48 KB -> 3 blocks/CU.
// ---------------------------------------------------------------------------
__global__ __launch_bounds__(256, 3) void attn_kernel(const short* __restrict__ Q,
                                                      const short* __restrict__ Kb,
                                                      const short* __restrict__ VT,
                                                      short* __restrict__ CC) {
    __shared__ alignas(16) short Kt[128 * 64];   // swizzled chunks
    __shared__ alignas(16) short Vt[64 * 128];   // swizzled chunks
    __shared__ alignas(16) short Pt[128 * 64];   // 16 KB: row = nq*64 + w*16 + lm, 64 t-cols per mg
    int bh = blockIdx.x;
    int qt = 15 - blockIdx.y;
    int b = bh >> 4, h = bh & 15;
    int tid = threadIdx.x;
    int w = tid >> 6, l = tid & 63;
    int quad = l >> 4, lm = l & 15;
    int lmx = lm & 7;
    int rsub = l >> 3;              // K staging row-within-8
    int csw = ((l & 7) ^ rsub) * 8; // K staging swizzled chunk offset
    int vr4 = l >> 4;               // V staging row-within-4
    int vc = l & 15;

    const short* Qbh = Q + (size_t)bh * S_ * DH_;
    const short* Kbh = Kb + (size_t)bh * S_ * DH_;
    const short* Vbh = VT + (size_t)bh * 64 * S_;

    int q0 = qt * 128;

    short8 qa[2][2];
#pragma unroll
    for (int nq = 0; nq < 2; ++nq) {
        const short* Qrow = Qbh + (size_t)(q0 + nq * 64 + w * 16 + lm) * DH_;
        qa[nq][0] = *(const short8*)(Qrow + quad * 8);
        qa[nq][1] = *(const short8*)(Qrow + 32 + quad * 8);
    }

    floatx4 acc_o[2][4];
#pragma unroll
    for (int nq = 0; nq < 2; ++nq)
#pragma unroll
        for (int ct = 0; ct < 4; ++ct) acc_o[nq][ct] = (floatx4)0.0f;
    float lsum[2] = {0.0f, 0.0f};

    int nkt = qt + 1;
    for (int kt = 0; kt < nkt; ++kt) {
        int t0 = kt * 128;
        // stage Kt[128][64] (rows contiguous) and Vt[64][128] (rows stride S_)
        const short* Ktile = Kbh + (size_t)t0 * DH_;
#pragma unroll
        for (int i = 0; i < 4; ++i) {
            int r0 = w * 32 + i * 8;
            const short* ga = Ktile + (size_t)(r0 + rsub) * 64 + csw;
            __builtin_amdgcn_global_load_lds((const __attribute__((address_space(1))) void*)ga,
                                             (__attribute__((address_space(3))) void*)(Kt + r0 * 64),
                                             16, 0, 0);
        }
#pragma unroll
        for (int i = 0; i < 4; ++i) {
            int r0v = w * 16 + i * 4;
            int row = r0v + vr4;
            const short* gv = Vbh + (size_t)row * S_ + t0 + ((vc ^ (row & 7)) * 8);
            __builtin_amdgcn_global_load_lds((const __attribute__((address_space(1))) void*)gv,
                                             (__attribute__((address_space(3))) void*)(Vt + r0v * 128),
                                             16, 0, 0);
        }
        __syncthreads();

        bool last = (kt == nkt - 1);
#pragma unroll
        for (int mg = 0; mg < 2; ++mg) {
            // K-frags for this mt-half: 32 VGPR transient, reused for both q-halves
            short8 kf[4][2];
#pragma unroll
            for (int mi = 0; mi < 4; ++mi)
#pragma unroll
                for (int ks = 0; ks < 2; ++ks)
                    kf[mi][ks] = *(const short8*)(Kt + ((mg * 4 + mi) * 16 + lm) * 64 +
                                                  (((ks * 4 + quad) ^ lmx) << 3));
            short8 pa[2][2];
#pragma unroll
            for (int nq = 0; nq < 2; ++nq) {
                floatx4 sc[4];
                __builtin_amdgcn_s_setprio(1);
#pragma unroll
                for (int mi = 0; mi < 4; ++mi) {
                    floatx4 t = (floatx4)0.0f;
                    t = __builtin_amdgcn_mfma_f32_16x16x32_bf16(kf[mi][0], qa[nq][0], t, 0, 0, 0);
                    t = __builtin_amdgcn_mfma_f32_16x16x32_bf16(kf[mi][1], qa[nq][1], t, 0, 0, 0);
                    sc[mi] = t;  // S^T: row=t (quad*4+r), col=q (lm)
                }
                __builtin_amdgcn_s_setprio(0);
                if (last) {
                    int q_ = q0 + nq * 64 + w * 16 + lm;
#pragma unroll
                    for (int mi = 0; mi < 4; ++mi)
#pragma unroll
                        for (int r = 0; r < 4; ++r) {
                            int t_ = t0 + (mg * 4 + mi) * 16 + quad * 4 + r;
                            if (t_ > q_) sc[mi][r] = -INFINITY;
                        }
                }
                int prow = nq * 64 + w * 16 + lm;
#pragma unroll
                for (int mi = 0; mi < 4; ++mi) {
                    float p0 = exp2f(sc[mi][0]);
                    float p1 = exp2f(sc[mi][1]);
                    float p2 = exp2f(sc[mi][2]);
                    float p3 = exp2f(sc[mi][3]);
                    lsum[nq] += (p0 + p1) + (p2 + p3);
                    short4x pk;
                    pk[0] = f2bf_rz(p0); pk[1] = f2bf_rz(p1);
                    pk[2] = f2bf_rz(p2); pk[3] = f2bf_rz(p3);
                    int c = mi * 2 + (quad >> 1);
                    *(short4x*)(Pt + prow * 64 + ((c ^ lmx) << 3) + (quad & 1) * 4) = pk;
                }
                // Pt rows are (nq,wave)-private -> no barrier, no aliasing:
                // same-wave DS ops to the same rows are program-ordered.
#pragma unroll
                for (int kk = 0; kk < 2; ++kk)
                    pa[nq][kk] = *(const short8*)(Pt + prow * 64 + (((kk * 4 + quad) ^ lmx) << 3));
            }
            __builtin_amdgcn_s_setprio(1);
#pragma unroll
            for (int ct = 0; ct < 4; ++ct) {
                const short* vrow = Vt + (ct * 16 + lm) * 128;
#pragma unroll
                for (int kk = 0; kk < 2; ++kk) {
                    int ks = mg * 2 + kk;
                    short8 v = *(const short8*)(vrow + (((ks * 4 + quad) ^ lmx) << 3));
                    acc_o[0][ct] = __builtin_amdgcn_mfma_f32_16x16x32_bf16(pa[0][kk], v, acc_o[0][ct], 0, 0, 0);
                    acc_o[1][ct] = __builtin_amdgcn_mfma_f32_16x16x32_bf16(pa[1][kk], v, acc_o[1][ct], 0, 0, 0);
                }
            }
            __builtin_amdgcn_s_setprio(0);
        }
        __syncthreads();  // protects Kt/Vt restage next iteration
    }

    // reduce l across quads (lanes with same lm), then 1/l
    float invl[2];
#pragma unroll
    for (int nq = 0; nq < 2; ++nq) {
        float lr = lsum[nq];
        lr += __shfl_xor(lr, 16);
        lr += __shfl_xor(lr, 32);
        invl[nq] = 1.0f / lr;
    }

#pragma unroll
    for (int nq = 0; nq < 2; ++nq) {
#pragma unroll
        for (int r = 0; r < 4; ++r) {
            float iv = __shfl(invl[nq], quad * 4 + r);  // l for q-row quad*4+r
            int row = q0 + nq * 64 + w * 16 + quad * 4 + r;
            short* OC = CC + ((size_t)b * S_ + row) * D_ + h * DH_;
#pragma unroll
            for (int ct = 0; ct < 4; ++ct)
                OC[ct * 16 + lm] = f2bf(acc_o[nq][ct][r] * iv);
        }
    }
}

extern "C" void kernel_launch(void* const* d_in, const int* in_sizes, int n_in,
                              void* d_out, int out_size, void* d_ws, size_t ws_size,
                              hipStream_t stream) {
    const float* x  = (const float*)d_in[0];
    const float* Wq = (const float*)d_in[1];
    const float* Wk = (const float*)d_in[2];
    const float* Wv = (const float*)d_in[3];
    const float* Wo = (const float*)d_in[4];
    const float* bo = (const float*)d_in[5];
    float* out = (float*)d_out;
    short* ws = (short*)d_ws;

    const size_t WSZ = (size_t)H_ * D_ * DH_;        // 1,048,576
    const size_t QSZ = (size_t)B_ * H_ * S_ * DH_;   // 8,388,608
    short* WqT = ws;
    short* WkT = WqT + WSZ;
    short* WvT = WkT + WSZ;
    short* WoT = WvT + WSZ;
    short* xb  = WoT + (size_t)D_ * D_;
    short* Qb  = xb + (size_t)B_ * S_ * D_;
    short* Kb  = Qb + QSZ;
    short* VTb = Kb + QSZ;
    short* CCb = VTb + QSZ;

    convert_x<<<(B_ * S_ * D_ / 8 + 255) / 256, 256, 0, stream>>>(x, xb, B_ * S_ * D_ / 8);
    prep_weights<<<dim3(16, 16, 4), 256, 0, stream>>>(Wq, Wk, Wv, Wo, WqT, WkT, WvT, WoT);
    qkv_gemm128<<<dim3(64, 8, 3), 256, 0, stream>>>(xb, WqT, WkT, WvT, Qb, Kb, VTb);
    attn_kernel<<<dim3(64, 16), 256, 0, stream>>>(Qb, Kb, VTb, CCb);
    outproj128<<<dim3(64, 8), 256, 0, stream>>>(CCb, WoT, bo, out);
}

// Round 6
// 247.016 us; speedup vs baseline: 1.2270x; 1.1952x over previous
//
#include <hip/hip_runtime.h>
#include <hip/hip_bf16.h>

typedef __attribute__((ext_vector_type(8))) short short8;
typedef __attribute__((ext_vector_type(4))) short short4x;
typedef __attribute__((ext_vector_type(4))) float floatx4;

__device__ __forceinline__ short f2bf(float f) {
    unsigned u = __float_as_uint(f);
    u = u + 0x7fffu + ((u >> 16) & 1u);
    return (short)(u >> 16);
}
// truncating convert (values >=0, used for P only)
__device__ __forceinline__ short f2bf_rz(float f) {
    return (short)(__float_as_uint(f) >> 16);
}

static constexpr int B_ = 4, S_ = 2048, D_ = 1024, H_ = 16, DH_ = 64;
// Q pre-scale: 1/sqrt(DH) * log2(e), so attention scores are in log2 domain
static constexpr float QSCALE = 0.125f * 1.4426950408889634f;

// ---------------------------------------------------------------------------
// x convert: f32 -> bf16, 8 elements/thread
// ---------------------------------------------------------------------------
__global__ __launch_bounds__(256) void convert_x(const float* __restrict__ in,
                                                 short* __restrict__ out, int n8) {
    int i = blockIdx.x * 256 + threadIdx.x;
    if (i >= n8) return;
    const float4* p = (const float4*)(in + (size_t)i * 8);
    float4 a = p[0], b = p[1];
    short8 v;
    v[0] = f2bf(a.x); v[1] = f2bf(a.y); v[2] = f2bf(a.z); v[3] = f2bf(a.w);
    v[4] = f2bf(b.x); v[5] = f2bf(b.y); v[6] = f2bf(b.z); v[7] = f2bf(b.w);
    *(short8*)(out + (size_t)i * 8) = v;
}

// ---------------------------------------------------------------------------
// Merged weight prep: transpose + f32->bf16 for Wq/Wk/Wv (z=0..2, y=head) and
// Wo (z=3, y=n-tile). grid (16, 16, 4).
// ---------------------------------------------------------------------------
__global__ __launch_bounds__(256) void prep_weights(const float* __restrict__ Wq,
                                                    const float* __restrict__ Wk,
                                                    const float* __restrict__ Wv,
                                                    const float* __restrict__ Wo,
                                                    short* __restrict__ WqT,
                                                    short* __restrict__ WkT,
                                                    short* __restrict__ WvT,
                                                    short* __restrict__ WoT) {
    __shared__ alignas(16) float t[64 * 68];
    int z = blockIdx.z;
    const float* in;
    short* out;
    int N, M = D_, n0;
    if (z < 3) {
        const float* I = (z == 0) ? Wq : (z == 1) ? Wk : Wv;
        short* O = (z == 0) ? WqT : (z == 1) ? WkT : WvT;
        in = I + (size_t)blockIdx.y * D_ * DH_;
        out = O + (size_t)blockIdx.y * D_ * DH_;
        N = DH_; n0 = 0;
    } else {
        in = Wo; out = WoT; N = D_; n0 = blockIdx.y * 64;
    }
    int m0 = blockIdx.x * 64;
    int tid = threadIdx.x;
#pragma unroll
    for (int i = 0; i < 4; ++i) {
        int c = tid + i * 256;
        int row = c >> 4, c4 = (c & 15) * 4;
        float4 v = *(const float4*)(in + (size_t)(m0 + row) * N + n0 + c4);
        *(float4*)(t + row * 68 + c4) = v;
    }
    __syncthreads();
#pragma unroll
    for (int i = 0; i < 2; ++i) {
        int c = tid + i * 256;
        int row = c >> 3, c8 = (c & 7) * 8;
        short8 v;
#pragma unroll
        for (int j = 0; j < 8; ++j) v[j] = f2bf(t[(c8 + j) * 68 + row]);
        *(short8*)(out + (size_t)(n0 + row) * M + m0 + c8) = v;
    }
}

// ---------------------------------------------------------------------------
// m97-style 128x128 GEMM core with XOR-swizzled LDS chunks (validated r6:
// conflicts 1.9e7 -> 2e5).
// ---------------------------------------------------------------------------
__device__ __forceinline__ void gemm128_core(const short* __restrict__ A,
                                             const short* __restrict__ Bm,
                                             short* ldsA, short* ldsB,
                                             int m0, int n0,
                                             floatx4 (&acc)[4][4],
                                             int w, int lane, int quad, int lm) {
    const int K = 1024;
    int wm = (w >> 1) * 64, wn = (w & 1) * 64;
    int rsub = lane >> 3;                       // row-within-8-group
    int csw = ((lane & 7) ^ rsub) * 8;          // swizzled global k-chunk offset (shorts)
    int lmx = lm & 7;                           // reader swizzle key
    for (int k0 = 0; k0 < K; k0 += 64) {
#pragma unroll
        for (int i = 0; i < 4; ++i) {
            int r0 = w * 32 + i * 8;
            const short* ga = A + (size_t)(m0 + r0 + rsub) * K + k0 + csw;
            __builtin_amdgcn_global_load_lds((const __attribute__((address_space(1))) void*)ga,
                                             (__attribute__((address_space(3))) void*)(ldsA + r0 * 64),
                                             16, 0, 0);
            const short* gb = Bm + (size_t)(n0 + r0 + rsub) * K + k0 + csw;
            __builtin_amdgcn_global_load_lds((const __attribute__((address_space(1))) void*)gb,
                                             (__attribute__((address_space(3))) void*)(ldsB + r0 * 64),
                                             16, 0, 0);
        }
        __syncthreads();
#pragma unroll
        for (int ks = 0; ks < 2; ++ks) {
            short8 am[4], bn[4];
#pragma unroll
            for (int i = 0; i < 4; ++i)
                am[i] = *(const short8*)(ldsA + (wm + i * 16 + lm) * 64 + (((ks * 4 + quad) ^ lmx) << 3));
#pragma unroll
            for (int i = 0; i < 4; ++i)
                bn[i] = *(const short8*)(ldsB + (wn + i * 16 + lm) * 64 + (((ks * 4 + quad) ^ lmx) << 3));
#pragma unroll
            for (int mi = 0; mi < 4; ++mi)
#pragma unroll
                for (int ni = 0; ni < 4; ++ni)
                    acc[mi][ni] = __builtin_amdgcn_mfma_f32_16x16x32_bf16(am[mi], bn[ni], acc[mi][ni], 0, 0, 0);
        }
        __syncthreads();
    }
}

// ---------------------------------------------------------------------------
// QKV projection: grid (64, 8, 3). A = xb [8192][1024]. B = W?T [1024 n][1024 k].
// z=0 -> Q[b,h,s,e] pre-scaled by QSCALE; z=1 -> K[b,h,s,e]; z=2 -> VT[(b*1024+n)][s]
// ---------------------------------------------------------------------------
__global__ __launch_bounds__(256, 4) void qkv_gemm128(const short* __restrict__ xb,
                                                      const short* __restrict__ WqT,
                                                      const short* __restrict__ WkT,
                                                      const short* __restrict__ WvT,
                                                      short* __restrict__ Q,
                                                      short* __restrict__ K,
                                                      short* __restrict__ VT) {
    __shared__ alignas(16) short lds[16384];  // 32 KB: staging A|B, reused as epilogue bounce
    short* ldsA = lds;
    short* ldsB = lds + 8192;
    int m0 = blockIdx.x * 128, n0 = blockIdx.y * 128, z = blockIdx.z;
    const short* Bm = (z == 0) ? WqT : (z == 1) ? WkT : WvT;
    int tid = threadIdx.x, w = tid >> 6, lane = tid & 63, quad = lane >> 4, lm = lane & 15;

    floatx4 acc[4][4];
#pragma unroll
    for (int mi = 0; mi < 4; ++mi)
#pragma unroll
        for (int ni = 0; ni < 4; ++ni) acc[mi][ni] = (floatx4)0.0f;

    gemm128_core(xb, Bm, ldsA, ldsB, m0, n0, acc, w, lane, quad, lm);

    int wm = (w >> 1) * 64, wn = (w & 1) * 64;
    int b = m0 >> 11;
    int sbase = m0 & 2047;

    if (z < 2) {
        short* O = (z == 0) ? Q : K;
        float scale = (z == 0) ? QSCALE : 1.0f;
        short* t = lds;  // 128 x 68
#pragma unroll
        for (int ph = 0; ph < 2; ++ph) {
            if (ph) __syncthreads();
            if ((w & 1) == ph) {
#pragma unroll
                for (int mi = 0; mi < 4; ++mi)
#pragma unroll
                    for (int ni = 0; ni < 4; ++ni)
#pragma unroll
                        for (int r = 0; r < 4; ++r)
                            t[(wm + mi * 16 + quad * 4 + r) * 68 + ni * 16 + lm] =
                                f2bf(acc[mi][ni][r] * scale);
            }
            __syncthreads();
            int h = (n0 + ph * 64) >> 6;
            size_t obase = ((size_t)(b * 16 + h) * 2048 + sbase) * 64;
#pragma unroll
            for (int i = 0; i < 4; ++i) {
                int c = tid + i * 256;
                int m = c >> 3, e8 = (c & 7) * 8;
                short8 v = *(const short8*)(t + m * 68 + e8);
                *(short8*)(O + obase + (size_t)m * 64 + e8) = v;
            }
        }
    } else {
        // transpose 128x128 tile through LDS (two 64-n halves) -> VT[b*1024+n][s]
        short* t = lds;  // 64 x 136
#pragma unroll
        for (int ph = 0; ph < 2; ++ph) {
            if (ph) __syncthreads();
            if ((w & 1) == ph) {
#pragma unroll
                for (int mi = 0; mi < 4; ++mi)
#pragma unroll
                    for (int ni = 0; ni < 4; ++ni) {
                        int nl = ni * 16 + lm;
#pragma unroll
                        for (int r = 0; r < 4; ++r) {
                            int ml = wm + mi * 16 + quad * 4 + r;
                            t[nl * 136 + ml] = f2bf(acc[mi][ni][r]);
                        }
                    }
            }
            __syncthreads();
#pragma unroll
            for (int i = 0; i < 4; ++i) {
                int c = tid + i * 256;
                int rowl = c >> 4, colc = (c & 15) * 8;
                short8 v = *(const short8*)(t + rowl * 136 + colc);
                size_t n = n0 + ph * 64 + rowl;
                *(short8*)(VT + ((size_t)b * 1024 + n) * 2048 + sbase + colc) = v;
            }
        }
    }
}

// ---------------------------------------------------------------------------
// Output projection: out[8192][1024] f32 = CC @ WoT^T + bo. grid (64, 8).
// ---------------------------------------------------------------------------
__global__ __launch_bounds__(256, 4) void outproj128(const short* __restrict__ CC,
                                                     const short* __restrict__ WoT,
                                                     const float* __restrict__ bo,
                                                     float* __restrict__ out) {
    __shared__ alignas(16) short lds[16384];
    short* ldsA = lds;
    short* ldsB = lds + 8192;
    int m0 = blockIdx.x * 128, n0 = blockIdx.y * 128;
    int tid = threadIdx.x, w = tid >> 6, lane = tid & 63, quad = lane >> 4, lm = lane & 15;

    floatx4 acc[4][4];
#pragma unroll
    for (int mi = 0; mi < 4; ++mi)
#pragma unroll
        for (int ni = 0; ni < 4; ++ni) acc[mi][ni] = (floatx4)0.0f;

    gemm128_core(CC, WoT, ldsA, ldsB, m0, n0, acc, w, lane, quad, lm);

    int wm = (w >> 1) * 64, wn = (w & 1) * 64;
#pragma unroll
    for (int mi = 0; mi < 4; ++mi)
#pragma unroll
        for (int ni = 0; ni < 4; ++ni) {
            int n = n0 + wn + ni * 16 + lm;
            float bb = bo[n];
#pragma unroll
            for (int r = 0; r < 4; ++r) {
                int m = m0 + wm + mi * 16 + quad * 4 + r;
                out[(size_t)m * 1024 + n] = acc[mi][ni][r] + bb;
            }
        }
}

// ---------------------------------------------------------------------------
// Causal flash attention v9 == round-0 structure (78.6 us measured) + XCD-
// aware grid swap. r1-r5 lesson: 3 blocks/CU is unreachable for this kernel
// (reg demand vs 168-cap -> spill; or frag re-reads -> LDS-pipe bound).
// Revert to the proven (256,2) / 64 KB / kf-in-regs structure.
// Grid CHANGED from (pi=8, bh=64) to (bh=64, pi=8): bh fastest-varying means
// the 8 pi-blocks sharing a bh sit 64 apart -> SAME XCD (64 % 8 == 0); each
// XCD holds 8 bh x 512 KB K/V = 4 MB = its L2. v7 measured this mapping:
// FETCH 146 MB -> 52 MB. K/V staging then hits L2 (~200cy) not HBM (~900cy).
// s_setprio(1) around MFMA clusters (T5, +4-7% attn measured).
// LDS: Kt 16K + Vt 16K + Pt 32K = 64 KB -> 2 blocks/CU.
// ---------------------------------------------------------------------------
__global__ __launch_bounds__(256, 2) void attn_kernel(const short* __restrict__ Q,
                                                      const short* __restrict__ Kb,
                                                      const short* __restrict__ VT,
                                                      short* __restrict__ CC) {
    __shared__ alignas(16) short Kt[128 * 64];   // swizzled chunks
    __shared__ alignas(16) short Vt[64 * 128];   // swizzled chunks
    __shared__ alignas(16) short Pt[128 * 128];  // swizzled chunks
    int bh = blockIdx.x;
    int pi = blockIdx.y;
    int b = bh >> 4, h = bh & 15;
    int tid = threadIdx.x;
    int w = tid >> 6, l = tid & 63;
    int quad = l >> 4, lm = l & 15;
    int lmx = lm & 7;
    int rsub = l >> 3;              // K staging row-within-8
    int csw = ((l & 7) ^ rsub) * 8; // K staging swizzled chunk offset
    int vr4 = l >> 4;               // V staging row-within-4
    int vc = l & 15;

    const short* Qbh = Q + (size_t)bh * S_ * DH_;
    const short* Kbh = Kb + (size_t)bh * S_ * DH_;
    const short* Vbh = VT + (size_t)bh * 64 * S_;

    for (int ps = 0; ps < 2; ++ps) {
        int qt = ps ? (15 - pi) : pi;
        int q0 = qt * 128;

        short8 qa[2][2];
#pragma unroll
        for (int nq = 0; nq < 2; ++nq) {
            const short* Qrow = Qbh + (size_t)(q0 + nq * 64 + w * 16 + lm) * DH_;
            qa[nq][0] = *(const short8*)(Qrow + quad * 8);
            qa[nq][1] = *(const short8*)(Qrow + 32 + quad * 8);
        }

        floatx4 acc_o[2][4];
#pragma unroll
        for (int nq = 0; nq < 2; ++nq)
#pragma unroll
            for (int ct = 0; ct < 4; ++ct) acc_o[nq][ct] = (floatx4)0.0f;
        float lsum[2] = {0.0f, 0.0f};

        int nkt = qt + 1;
        for (int kt = 0; kt < nkt; ++kt) {
            int t0 = kt * 128;
            // stage Kt[128][64] (rows contiguous) and Vt[64][128] (rows stride S_)
            const short* Ktile = Kbh + (size_t)t0 * DH_;
#pragma unroll
            for (int i = 0; i < 4; ++i) {
                int r0 = w * 32 + i * 8;
                const short* ga = Ktile + (size_t)(r0 + rsub) * 64 + csw;
                __builtin_amdgcn_global_load_lds((const __attribute__((address_space(1))) void*)ga,
                                                 (__attribute__((address_space(3))) void*)(Kt + r0 * 64),
                                                 16, 0, 0);
            }
#pragma unroll
            for (int i = 0; i < 4; ++i) {
                int r0v = w * 16 + i * 4;
                int row = r0v + vr4;
                const short* gv = Vbh + (size_t)row * S_ + t0 + ((vc ^ (row & 7)) * 8);
                __builtin_amdgcn_global_load_lds((const __attribute__((address_space(1))) void*)gv,
                                                 (__attribute__((address_space(3))) void*)(Vt + r0v * 128),
                                                 16, 0, 0);
            }
            __syncthreads();

            // K-frags once, reused for both q-halves
            short8 kf[8][2];
#pragma unroll
            for (int mt = 0; mt < 8; ++mt)
#pragma unroll
                for (int ks = 0; ks < 2; ++ks)
                    kf[mt][ks] = *(const short8*)(Kt + (mt * 16 + lm) * 64 + (((ks * 4 + quad) ^ lmx) << 3));

            bool last = (kt == nkt - 1);
#pragma unroll
            for (int nq = 0; nq < 2; ++nq) {
                floatx4 sc[8];
                __builtin_amdgcn_s_setprio(1);
#pragma unroll
                for (int mt = 0; mt < 8; ++mt) {
                    floatx4 t = (floatx4)0.0f;
                    t = __builtin_amdgcn_mfma_f32_16x16x32_bf16(kf[mt][0], qa[nq][0], t, 0, 0, 0);
                    t = __builtin_amdgcn_mfma_f32_16x16x32_bf16(kf[mt][1], qa[nq][1], t, 0, 0, 0);
                    sc[mt] = t;  // S^T: row=t (quad*4+r), col=q (lm)
                }
                __builtin_amdgcn_s_setprio(0);
                if (last) {
                    int q_ = q0 + nq * 64 + w * 16 + lm;
#pragma unroll
                    for (int mt = 0; mt < 8; ++mt)
#pragma unroll
                        for (int r = 0; r < 4; ++r) {
                            int t_ = t0 + mt * 16 + quad * 4 + r;
                            if (t_ > q_) sc[mt][r] = -INFINITY;
                        }
                }
                int prow = nq * 64 + w * 16 + lm;
#pragma unroll
                for (int mt = 0; mt < 8; ++mt) {
                    float p0 = exp2f(sc[mt][0]);
                    float p1 = exp2f(sc[mt][1]);
                    float p2 = exp2f(sc[mt][2]);
                    float p3 = exp2f(sc[mt][3]);
                    lsum[nq] += (p0 + p1) + (p2 + p3);
                    short4x pk;
                    pk[0] = f2bf_rz(p0); pk[1] = f2bf_rz(p1);
                    pk[2] = f2bf_rz(p2); pk[3] = f2bf_rz(p3);
                    int c = mt * 2 + (quad >> 1);
                    *(short4x*)(Pt + prow * 128 + ((c ^ lmx) << 3) + (quad & 1) * 4) = pk;
                }
            }
            // Pt rows are wave-private -> no barrier between write and read
            short8 pa[2][4];
#pragma unroll
            for (int nq = 0; nq < 2; ++nq)
#pragma unroll
                for (int ks = 0; ks < 4; ++ks)
                    pa[nq][ks] = *(const short8*)(Pt + (nq * 64 + w * 16 + lm) * 128 +
                                                  (((ks * 4 + quad) ^ lmx) << 3));
            __builtin_amdgcn_s_setprio(1);
#pragma unroll
            for (int ct = 0; ct < 4; ++ct) {
                const short* vrow = Vt + (ct * 16 + lm) * 128;
#pragma unroll
                for (int ks = 0; ks < 4; ++ks) {
                    short8 v = *(const short8*)(vrow + (((ks * 4 + quad) ^ lmx) << 3));
                    acc_o[0][ct] = __builtin_amdgcn_mfma_f32_16x16x32_bf16(pa[0][ks], v, acc_o[0][ct], 0, 0, 0);
                    acc_o[1][ct] = __builtin_amdgcn_mfma_f32_16x16x32_bf16(pa[1][ks], v, acc_o[1][ct], 0, 0, 0);
                }
            }
            __builtin_amdgcn_s_setprio(0);
            __syncthreads();  // protects Kt/Vt restage next iteration
        }

        // reduce l across quads (lanes with same lm), then 1/l
        float invl[2];
#pragma unroll
        for (int nq = 0; nq < 2; ++nq) {
            float lr = lsum[nq];
            lr += __shfl_xor(lr, 16);
            lr += __shfl_xor(lr, 32);
            invl[nq] = 1.0f / lr;
        }

#pragma unroll
        for (int nq = 0; nq < 2; ++nq) {
#pragma unroll
            for (int r = 0; r < 4; ++r) {
                float iv = __shfl(invl[nq], quad * 4 + r);  // l for q-row quad*4+r
                int row = q0 + nq * 64 + w * 16 + quad * 4 + r;
                short* OC = CC + ((size_t)b * S_ + row) * D_ + h * DH_;
#pragma unroll
                for (int ct = 0; ct < 4; ++ct)
                    OC[ct * 16 + lm] = f2bf(acc_o[nq][ct][r] * iv);
            }
        }
    }
}

extern "C" void kernel_launch(void* const* d_in, const int* in_sizes, int n_in,
                              void* d_out, int out_size, void* d_ws, size_t ws_size,
                              hipStream_t stream) {
    const float* x  = (const float*)d_in[0];
    const float* Wq = (const float*)d_in[1];
    const float* Wk = (const float*)d_in[2];
    const float* Wv = (const float*)d_in[3];
    const float* Wo = (const float*)d_in[4];
    const float* bo = (const float*)d_in[5];
    float* out = (float*)d_out;
    short* ws = (short*)d_ws;

    const size_t WSZ = (size_t)H_ * D_ * DH_;        // 1,048,576
    const size_t QSZ = (size_t)B_ * H_ * S_ * DH_;   // 8,388,608
    short* WqT = ws;
    short* WkT = WqT + WSZ;
    short* WvT = WkT + WSZ;
    short* WoT = WvT + WSZ;
    short* xb  = WoT + (size_t)D_ * D_;
    short* Qb  = xb + (size_t)B_ * S_ * D_;
    short* Kb  = Qb + QSZ;
    short* VTb = Kb + QSZ;
    short* CCb = VTb + QSZ;

    convert_x<<<(B_ * S_ * D_ / 8 + 255) / 256, 256, 0, stream>>>(x, xb, B_ * S_ * D_ / 8);
    prep_weights<<<dim3(16, 16, 4), 256, 0, stream>>>(Wq, Wk, Wv, Wo, WqT, WkT, WvT, WoT);
    qkv_gemm128<<<dim3(64, 8, 3), 256, 0, stream>>>(xb, WqT, WkT, WvT, Qb, Kb, VTb);
    attn_kernel<<<dim3(64, 8), 256, 0, stream>>>(Qb, Kb, VTb, CCb);
    outproj128<<<dim3(64, 8), 256, 0, stream>>>(CCb, WoT, bo, out);
}